// Round 1
// baseline (10573.557 us; speedup 1.0000x reference)
//
#include <hip/hip_runtime.h>

#define N_NODES    100000
#define N_FEATURES 2000
#define HIDDEN     64
#define N_LABELS   16
#define NNZ_FEAT   5000000
#define N_EDGES    3200000
#define ITERS      10
#define ALPHA      0.1f

// ---------------- kernels ----------------

__global__ __launch_bounds__(256) void zero_f4(float4* __restrict__ p, int n4) {
    int t = blockIdx.x * 256 + threadIdx.x;
    if (t < n4) p[t] = make_float4(0.f, 0.f, 0.f, 0.f);
}

// One thread per (nnz, 4-dim group): 16 threads cover one nnz's 64 hidden dims.
// rows/cols/vals loads are same-address across the 16-thread group (broadcast).
__global__ __launch_bounds__(256) void spmm_feat_atomic(
    const int* __restrict__ rows, const int* __restrict__ cols,
    const float* __restrict__ vals, const float* __restrict__ W1,
    float* __restrict__ latent)
{
    long long t = (long long)blockIdx.x * 256 + threadIdx.x;
    if (t >= (long long)NNZ_FEAT * 16) return;
    int e  = (int)(t >> 4);
    int dg = (int)(t & 15);
    int r = rows[e];
    int c = cols[e];
    float v = vals[e];
    float4 w = *reinterpret_cast<const float4*>(W1 + (size_t)c * HIDDEN + dg * 4);
    float* dst = latent + (size_t)r * HIDDEN + dg * 4;
    atomicAdd(dst + 0, v * w.x);
    atomicAdd(dst + 1, v * w.y);
    atomicAdd(dst + 2, v * w.z);
    atomicAdd(dst + 3, v * w.w);
}

// z = relu(latent + b1) @ W2 + b2.  16 lanes per node (lane = label).
__global__ __launch_bounds__(256) void compute_z(
    const float* __restrict__ latent, const float* __restrict__ b1,
    const float* __restrict__ W2, const float* __restrict__ b2,
    float* __restrict__ z)
{
    __shared__ float sW2[HIDDEN * N_LABELS];
    __shared__ float sb1[HIDDEN];
    for (int i = threadIdx.x; i < HIDDEN * N_LABELS; i += 256) sW2[i] = W2[i];
    if (threadIdx.x < HIDDEN) sb1[threadIdx.x] = b1[threadIdx.x];
    __syncthreads();
    int t = blockIdx.x * 256 + threadIdx.x;
    int node = t >> 4;
    int l = t & 15;
    if (node >= N_NODES) return;
    float acc = b2[l];
    const float* lat = latent + (size_t)node * HIDDEN;
    #pragma unroll 8
    for (int h = 0; h < HIDDEN; ++h) {
        float a = lat[h] + sb1[h];
        a = a > 0.f ? a : 0.f;
        acc = fmaf(a, sW2[h * N_LABELS + l], acc);
    }
    z[(size_t)node * N_LABELS + l] = acc;
}

// acc = ALPHA * z  (the +alpha*z term of the APPNP step, pre-seeded)
__global__ __launch_bounds__(256) void init_acc(const float* __restrict__ z,
                                                float* __restrict__ acc) {
    int t = blockIdx.x * 256 + threadIdx.x;
    if (t < N_NODES * N_LABELS / 4) {
        float4 zv = reinterpret_cast<const float4*>(z)[t];
        reinterpret_cast<float4*>(acc)[t] =
            make_float4(ALPHA * zv.x, ALPHA * zv.y, ALPHA * zv.z, ALPHA * zv.w);
    }
}

// acc[r] += (1-alpha) * w * p[c]   — 4 threads per edge (4 dims each)
__global__ __launch_bounds__(256) void edge_scatter(
    const int* __restrict__ rows, const int* __restrict__ cols,
    const float* __restrict__ w, const float* __restrict__ p,
    float* __restrict__ acc)
{
    long long t = (long long)blockIdx.x * 256 + threadIdx.x;
    if (t >= (long long)N_EDGES * 4) return;
    int e = (int)(t >> 2);
    int part = (int)(t & 3);
    int r = rows[e];
    int c = cols[e];
    float wt = w[e] * (1.0f - ALPHA);
    float4 pv = *reinterpret_cast<const float4*>(p + (size_t)c * N_LABELS + part * 4);
    float* dst = acc + (size_t)r * N_LABELS + part * 4;
    atomicAdd(dst + 0, wt * pv.x);
    atomicAdd(dst + 1, wt * pv.y);
    atomicAdd(dst + 2, wt * pv.z);
    atomicAdd(dst + 3, wt * pv.w);
}

__global__ __launch_bounds__(256) void logsoftmax_k(const float* __restrict__ p,
                                                    float* __restrict__ out) {
    int node = blockIdx.x * 256 + threadIdx.x;
    if (node >= N_NODES) return;
    const float4* src = reinterpret_cast<const float4*>(p + (size_t)node * N_LABELS);
    float4 a = src[0], b = src[1], c = src[2], d = src[3];
    float x[16] = {a.x,a.y,a.z,a.w, b.x,b.y,b.z,b.w, c.x,c.y,c.z,c.w, d.x,d.y,d.z,d.w};
    float m = x[0];
    #pragma unroll
    for (int i = 1; i < 16; ++i) m = fmaxf(m, x[i]);
    float s = 0.f;
    #pragma unroll
    for (int i = 0; i < 16; ++i) s += __expf(x[i] - m);
    float lse = m + __logf(s);
    float4* o = reinterpret_cast<float4*>(out + (size_t)node * N_LABELS);
    o[0] = make_float4(x[0]-lse,  x[1]-lse,  x[2]-lse,  x[3]-lse);
    o[1] = make_float4(x[4]-lse,  x[5]-lse,  x[6]-lse,  x[7]-lse);
    o[2] = make_float4(x[8]-lse,  x[9]-lse,  x[10]-lse, x[11]-lse);
    o[3] = make_float4(x[12]-lse, x[13]-lse, x[14]-lse, x[15]-lse);
}

// ---------------- launch ----------------

extern "C" void kernel_launch(void* const* d_in, const int* in_sizes, int n_in,
                              void* d_out, int out_size, void* d_ws, size_t ws_size,
                              hipStream_t stream)
{
    const int*   feat_rows = (const int*)d_in[0];
    const int*   feat_cols = (const int*)d_in[1];
    const float* feat_vals = (const float*)d_in[2];
    const int*   edge_rows = (const int*)d_in[3];
    const int*   edge_cols = (const int*)d_in[4];
    const float* edge_w    = (const float*)d_in[5];
    const float* W1 = (const float*)d_in[6];
    const float* b1 = (const float*)d_in[7];
    const float* W2 = (const float*)d_in[8];
    const float* b2 = (const float*)d_in[9];
    float* out = (float*)d_out;

    // ws layout (floats): latent[100000*64] | z[100000*16] | p0 | p1
    float* latent = (float*)d_ws;
    float* z  = latent + (size_t)N_NODES * HIDDEN;
    float* p0 = z  + (size_t)N_NODES * N_LABELS;
    float* p1 = p0 + (size_t)N_NODES * N_LABELS;

    // 1) latent = 0
    {
        int n4 = N_NODES * HIDDEN / 4;
        zero_f4<<<(n4 + 255) / 256, 256, 0, stream>>>((float4*)latent, n4);
    }
    // 2) latent += sparse_feat @ W1   (atomic scatter)
    {
        long long total = (long long)NNZ_FEAT * 16;
        int blocks = (int)((total + 255) / 256);
        spmm_feat_atomic<<<blocks, 256, 0, stream>>>(feat_rows, feat_cols, feat_vals, W1, latent);
    }
    // 3) z = relu(latent + b1) @ W2 + b2
    compute_z<<<(N_NODES * 16 + 255) / 256, 256, 0, stream>>>(latent, b1, W2, b2, z);

    // 4) 10 APPNP iterations: p_next = (1-a) * A@p + a*z
    const float* pin = z;
    float* bufs[2] = {p0, p1};
    for (int it = 0; it < ITERS; ++it) {
        float* pout = bufs[it & 1];
        init_acc<<<(N_NODES * N_LABELS / 4 + 255) / 256, 256, 0, stream>>>(z, pout);
        long long total = (long long)N_EDGES * 4;
        edge_scatter<<<(int)((total + 255) / 256), 256, 0, stream>>>(
            edge_rows, edge_cols, edge_w, pin, pout);
        pin = pout;
    }

    // 5) log_softmax
    logsoftmax_k<<<(N_NODES + 255) / 256, 256, 0, stream>>>(pin, out);
}

// Round 2
// 2151.811 us; speedup vs baseline: 4.9138x; 4.9138x over previous
//
#include <hip/hip_runtime.h>

#define N_NODES    100000
#define N_FEATURES 2000
#define HIDDEN     64
#define N_LABELS   16
#define NNZ_FEAT   5000000
#define N_EDGES    3200000
#define ITERS      10
#define ALPHA      0.1f

// ======================= CSR-build kernels =======================

__global__ __launch_bounds__(256) void zero_int(int* __restrict__ p, int n) {
    int t = blockIdx.x * 256 + threadIdx.x;
    if (t < n) p[t] = 0;
}

__global__ __launch_bounds__(256) void hist_k(const int* __restrict__ rows,
                                              int* __restrict__ cnt, int n) {
    int t = blockIdx.x * 256 + threadIdx.x;
    if (t < n) atomicAdd(&cnt[rows[t]], 1);
}

// Single-block exclusive scan over n counters -> rp[0..n] and cursor copy.
__global__ __launch_bounds__(1024) void scan_fill(const int* __restrict__ cnt,
                                                  int* __restrict__ rp,
                                                  int* __restrict__ cursor, int n) {
    __shared__ int sp[1024];
    int tid = threadIdx.x;
    int chunk = (n + 1023) >> 10;
    int lo = tid * chunk;
    int hi = lo + chunk; if (hi > n) hi = n;
    int s = 0;
    for (int i = lo; i < hi; ++i) s += cnt[i];
    sp[tid] = s;
    __syncthreads();
    for (int off = 1; off < 1024; off <<= 1) {
        int add = (tid >= off) ? sp[tid - off] : 0;
        __syncthreads();
        sp[tid] += add;
        __syncthreads();
    }
    int run = sp[tid] - s;  // exclusive base for this chunk
    for (int i = lo; i < hi; ++i) {
        int c = cnt[i];
        rp[i] = run; cursor[i] = run;
        run += c;
    }
    if (tid == 0) rp[n] = sp[1023];
}

// out[pos] = (col, val*scale) at pos = cursor[row]++
__global__ __launch_bounds__(256) void scatter_k(const int* __restrict__ rows,
                                                 const int* __restrict__ cols,
                                                 const float* __restrict__ vals,
                                                 int* __restrict__ cursor,
                                                 int2* __restrict__ out, int n, float scale) {
    int t = blockIdx.x * 256 + threadIdx.x;
    if (t >= n) return;
    int r = rows[t];
    int pos = atomicAdd(&cursor[r], 1);
    out[pos] = make_int2(cols[t], __float_as_int(vals[t] * scale));
}

// ======================= compute kernels =======================

// latent[row] = sum_e val_e * W1[col_e]   — 16 lanes/row, float4 acc per lane
__global__ __launch_bounds__(256) void spmm_csr(const int* __restrict__ rp,
                                                const int2* __restrict__ cw,
                                                const float* __restrict__ W1,
                                                float* __restrict__ latent) {
    int t = blockIdx.x * 256 + threadIdx.x;
    int row = t >> 4, lane = t & 15;
    if (row >= N_NODES) return;
    int s = rp[row], e = rp[row + 1];
    float4 acc = make_float4(0.f, 0.f, 0.f, 0.f);
    int i = s;
    for (; i + 1 < e; i += 2) {
        int2 a = cw[i], b = cw[i + 1];
        float4 wa = *reinterpret_cast<const float4*>(W1 + (size_t)a.x * HIDDEN + lane * 4);
        float4 wb = *reinterpret_cast<const float4*>(W1 + (size_t)b.x * HIDDEN + lane * 4);
        float va = __int_as_float(a.y), vb = __int_as_float(b.y);
        acc.x = fmaf(va, wa.x, acc.x); acc.y = fmaf(va, wa.y, acc.y);
        acc.z = fmaf(va, wa.z, acc.z); acc.w = fmaf(va, wa.w, acc.w);
        acc.x = fmaf(vb, wb.x, acc.x); acc.y = fmaf(vb, wb.y, acc.y);
        acc.z = fmaf(vb, wb.z, acc.z); acc.w = fmaf(vb, wb.w, acc.w);
    }
    if (i < e) {
        int2 a = cw[i];
        float4 wa = *reinterpret_cast<const float4*>(W1 + (size_t)a.x * HIDDEN + lane * 4);
        float va = __int_as_float(a.y);
        acc.x = fmaf(va, wa.x, acc.x); acc.y = fmaf(va, wa.y, acc.y);
        acc.z = fmaf(va, wa.z, acc.z); acc.w = fmaf(va, wa.w, acc.w);
    }
    *reinterpret_cast<float4*>(latent + (size_t)row * HIDDEN + lane * 4) = acc;
}

// z = relu(latent + b1) @ W2 + b2.  16 lanes per node (lane = label).
__global__ __launch_bounds__(256) void compute_z(const float* __restrict__ latent,
                                                 const float* __restrict__ b1,
                                                 const float* __restrict__ W2,
                                                 const float* __restrict__ b2,
                                                 float* __restrict__ z) {
    __shared__ float sW2[HIDDEN * N_LABELS];
    __shared__ float sb1[HIDDEN];
    for (int i = threadIdx.x; i < HIDDEN * N_LABELS; i += 256) sW2[i] = W2[i];
    if (threadIdx.x < HIDDEN) sb1[threadIdx.x] = b1[threadIdx.x];
    __syncthreads();
    int t = blockIdx.x * 256 + threadIdx.x;
    int node = t >> 4;
    int l = t & 15;
    if (node >= N_NODES) return;
    float acc = b2[l];
    const float* lat = latent + (size_t)node * HIDDEN;
    #pragma unroll 8
    for (int h = 0; h < HIDDEN; ++h) {
        float a = lat[h] + sb1[h];
        a = a > 0.f ? a : 0.f;
        acc = fmaf(a, sW2[h * N_LABELS + l], acc);
    }
    z[(size_t)node * N_LABELS + l] = acc;
}

// pout[row][l] = ALPHA*z[row][l] + sum_e (0.9*w_e) * pin[col_e][l]  — 16 lanes/row
__global__ __launch_bounds__(256) void prop_csr(const int* __restrict__ rp,
                                                const int2* __restrict__ cw,
                                                const float* __restrict__ z,
                                                const float* __restrict__ pin,
                                                float* __restrict__ pout) {
    int t = blockIdx.x * 256 + threadIdx.x;
    int row = t >> 4, l = t & 15;
    if (row >= N_NODES) return;
    int s = rp[row], e = rp[row + 1];
    int idx = row * N_LABELS + l;
    float acc = ALPHA * z[idx];
    int i = s;
    for (; i + 1 < e; i += 2) {
        int2 a = cw[i], b = cw[i + 1];
        float pa = pin[(size_t)a.x * N_LABELS + l];
        float pb = pin[(size_t)b.x * N_LABELS + l];
        acc = fmaf(__int_as_float(a.y), pa, acc);
        acc = fmaf(__int_as_float(b.y), pb, acc);
    }
    if (i < e) {
        int2 a = cw[i];
        acc = fmaf(__int_as_float(a.y), pin[(size_t)a.x * N_LABELS + l], acc);
    }
    pout[idx] = acc;
}

__global__ __launch_bounds__(256) void logsoftmax_k(const float* __restrict__ p,
                                                    float* __restrict__ out) {
    int node = blockIdx.x * 256 + threadIdx.x;
    if (node >= N_NODES) return;
    const float4* src = reinterpret_cast<const float4*>(p + (size_t)node * N_LABELS);
    float4 a = src[0], b = src[1], c = src[2], d = src[3];
    float x[16] = {a.x,a.y,a.z,a.w, b.x,b.y,b.z,b.w, c.x,c.y,c.z,c.w, d.x,d.y,d.z,d.w};
    float m = x[0];
    #pragma unroll
    for (int i = 1; i < 16; ++i) m = fmaxf(m, x[i]);
    float s = 0.f;
    #pragma unroll
    for (int i = 0; i < 16; ++i) s += __expf(x[i] - m);
    float lse = m + __logf(s);
    float4* o = reinterpret_cast<float4*>(out + (size_t)node * N_LABELS);
    o[0] = make_float4(x[0]-lse,  x[1]-lse,  x[2]-lse,  x[3]-lse);
    o[1] = make_float4(x[4]-lse,  x[5]-lse,  x[6]-lse,  x[7]-lse);
    o[2] = make_float4(x[8]-lse,  x[9]-lse,  x[10]-lse, x[11]-lse);
    o[3] = make_float4(x[12]-lse, x[13]-lse, x[14]-lse, x[15]-lse);
}

// ======================= fallback (R1 atomic path) =======================

__global__ __launch_bounds__(256) void zero_f4(float4* __restrict__ p, int n4) {
    int t = blockIdx.x * 256 + threadIdx.x;
    if (t < n4) p[t] = make_float4(0.f, 0.f, 0.f, 0.f);
}

__global__ __launch_bounds__(256) void spmm_feat_atomic(
    const int* __restrict__ rows, const int* __restrict__ cols,
    const float* __restrict__ vals, const float* __restrict__ W1,
    float* __restrict__ latent)
{
    long long t = (long long)blockIdx.x * 256 + threadIdx.x;
    if (t >= (long long)NNZ_FEAT * 16) return;
    int e  = (int)(t >> 4);
    int dg = (int)(t & 15);
    int r = rows[e]; int c = cols[e]; float v = vals[e];
    float4 w = *reinterpret_cast<const float4*>(W1 + (size_t)c * HIDDEN + dg * 4);
    float* dst = latent + (size_t)r * HIDDEN + dg * 4;
    atomicAdd(dst + 0, v * w.x); atomicAdd(dst + 1, v * w.y);
    atomicAdd(dst + 2, v * w.z); atomicAdd(dst + 3, v * w.w);
}

__global__ __launch_bounds__(256) void init_acc(const float* __restrict__ z,
                                                float* __restrict__ acc) {
    int t = blockIdx.x * 256 + threadIdx.x;
    if (t < N_NODES * N_LABELS / 4) {
        float4 zv = reinterpret_cast<const float4*>(z)[t];
        reinterpret_cast<float4*>(acc)[t] =
            make_float4(ALPHA * zv.x, ALPHA * zv.y, ALPHA * zv.z, ALPHA * zv.w);
    }
}

__global__ __launch_bounds__(256) void edge_scatter(
    const int* __restrict__ rows, const int* __restrict__ cols,
    const float* __restrict__ w, const float* __restrict__ p,
    float* __restrict__ acc)
{
    long long t = (long long)blockIdx.x * 256 + threadIdx.x;
    if (t >= (long long)N_EDGES * 4) return;
    int e = (int)(t >> 2);
    int part = (int)(t & 3);
    int r = rows[e]; int c = cols[e];
    float wt = w[e] * (1.0f - ALPHA);
    float4 pv = *reinterpret_cast<const float4*>(p + (size_t)c * N_LABELS + part * 4);
    float* dst = acc + (size_t)r * N_LABELS + part * 4;
    atomicAdd(dst + 0, wt * pv.x); atomicAdd(dst + 1, wt * pv.y);
    atomicAdd(dst + 2, wt * pv.z); atomicAdd(dst + 3, wt * pv.w);
}

// ======================= launch =======================

extern "C" void kernel_launch(void* const* d_in, const int* in_sizes, int n_in,
                              void* d_out, int out_size, void* d_ws, size_t ws_size,
                              hipStream_t stream)
{
    const int*   feat_rows = (const int*)d_in[0];
    const int*   feat_cols = (const int*)d_in[1];
    const float* feat_vals = (const float*)d_in[2];
    const int*   edge_rows = (const int*)d_in[3];
    const int*   edge_cols = (const int*)d_in[4];
    const float* edge_w    = (const float*)d_in[5];
    const float* W1 = (const float*)d_in[6];
    const float* b1 = (const float*)d_in[7];
    const float* W2 = (const float*)d_in[8];
    const float* b2 = (const float*)d_in[9];
    float* out = (float*)d_out;

    // ---- workspace layout (4-byte units), int2 arrays first for 8B alignment ----
    // feat_cw[2*NNZ] | edge_cw[2*E] | latent | z | p0 | p1 | feat_rp | edge_rp | cnt | cursor
    size_t need = 0;
    size_t o_feat_cw = need; need += (size_t)2 * NNZ_FEAT;
    size_t o_edge_cw = need; need += (size_t)2 * N_EDGES;
    size_t o_latent  = need; need += (size_t)N_NODES * HIDDEN;
    size_t o_z       = need; need += (size_t)N_NODES * N_LABELS;
    size_t o_p0      = need; need += (size_t)N_NODES * N_LABELS;
    size_t o_p1      = need; need += (size_t)N_NODES * N_LABELS;
    size_t o_frp     = need; need += N_NODES + 1;
    size_t o_erp     = need; need += N_NODES + 1;
    size_t o_cnt     = need; need += N_NODES;
    size_t o_cur     = need; need += N_NODES;
    size_t need_bytes = need * 4 + 64;

    float* base = (float*)d_ws;
    float* latent = base + o_latent;
    float* z  = base + o_z;
    float* p0 = base + o_p0;
    float* p1 = base + o_p1;

    if (ws_size >= need_bytes) {
        int2* feat_cw = (int2*)(base + o_feat_cw);
        int2* edge_cw = (int2*)(base + o_edge_cw);
        int* feat_rp = (int*)(base + o_frp);
        int* edge_rp = (int*)(base + o_erp);
        int* cnt     = (int*)(base + o_cnt);
        int* cursor  = (int*)(base + o_cur);

        // ---- feature CSR build ----
        zero_int<<<(N_NODES + 255) / 256, 256, 0, stream>>>(cnt, N_NODES);
        hist_k<<<(NNZ_FEAT + 255) / 256, 256, 0, stream>>>(feat_rows, cnt, NNZ_FEAT);
        scan_fill<<<1, 1024, 0, stream>>>(cnt, feat_rp, cursor, N_NODES);
        scatter_k<<<(NNZ_FEAT + 255) / 256, 256, 0, stream>>>(
            feat_rows, feat_cols, feat_vals, cursor, feat_cw, NNZ_FEAT, 1.0f);

        // ---- layer 1 + z ----
        spmm_csr<<<N_NODES * 16 / 256, 256, 0, stream>>>(feat_rp, feat_cw, W1, latent);
        compute_z<<<N_NODES * 16 / 256, 256, 0, stream>>>(latent, b1, W2, b2, z);

        // ---- edge CSR build (weights pre-scaled by 1-ALPHA) ----
        zero_int<<<(N_NODES + 255) / 256, 256, 0, stream>>>(cnt, N_NODES);
        hist_k<<<(N_EDGES + 255) / 256, 256, 0, stream>>>(edge_rows, cnt, N_EDGES);
        scan_fill<<<1, 1024, 0, stream>>>(cnt, edge_rp, cursor, N_NODES);
        scatter_k<<<(N_EDGES + 255) / 256, 256, 0, stream>>>(
            edge_rows, edge_cols, edge_w, cursor, edge_cw, N_EDGES, 1.0f - ALPHA);

        // ---- propagation ----
        const float* pin = z;
        float* bufs[2] = {p0, p1};
        for (int it = 0; it < ITERS; ++it) {
            float* pout = bufs[it & 1];
            prop_csr<<<N_NODES * 16 / 256, 256, 0, stream>>>(edge_rp, edge_cw, z, pin, pout);
            pin = pout;
        }
        logsoftmax_k<<<(N_NODES + 255) / 256, 256, 0, stream>>>(pin, out);
    } else {
        // ---- fallback: R1 atomic path (ws too small for CSR) ----
        int n4 = N_NODES * HIDDEN / 4;
        zero_f4<<<(n4 + 255) / 256, 256, 0, stream>>>((float4*)latent, n4);
        long long total = (long long)NNZ_FEAT * 16;
        spmm_feat_atomic<<<(int)((total + 255) / 256), 256, 0, stream>>>(
            feat_rows, feat_cols, feat_vals, W1, latent);
        compute_z<<<N_NODES * 16 / 256, 256, 0, stream>>>(latent, b1, W2, b2, z);
        const float* pin = z;
        float* bufs[2] = {p0, p1};
        for (int it = 0; it < ITERS; ++it) {
            float* pout = bufs[it & 1];
            init_acc<<<(N_NODES * N_LABELS / 4 + 255) / 256, 256, 0, stream>>>(z, pout);
            long long tot = (long long)N_EDGES * 4;
            edge_scatter<<<(int)((tot + 255) / 256), 256, 0, stream>>>(
                edge_rows, edge_cols, edge_w, pin, pout);
            pin = pout;
        }
        logsoftmax_k<<<(N_NODES + 255) / 256, 256, 0, stream>>>(pin, out);
    }
}